// Round 9
// baseline (4445.235 us; speedup 1.0000x reference)
//
#include <hip/hip_runtime.h>

// ---------------- problem constants ----------------
constexpr int B = 64, L = 512, E = 256, H = 512;
constexpr int ROWS = 4 * H;      // 2048 gate-rows (unit*4 + gate interleave)
constexpr int K    = E + H;      // 768
constexpr int K4   = K / 4;      // 192

// ---------------- ws layout (in floats) ----------------
constexpr size_t OFF_WT4   = 0;
constexpr size_t SZ_WT4    = (size_t)K4 * ROWS * 4;     // float4[K4][ROWS]
constexpr size_t OFF_BI    = OFF_WT4 + SZ_WT4;          // interleaved biases [ROWS]
constexpr size_t SZ_BI     = ROWS;
constexpr size_t OFF_H2    = OFF_BI + SZ_BI;            // TAGGED h dbuf [2][B][H] x (val,tag)
constexpr size_t SZ_H2     = (size_t)2 * B * H * 2;     // in floats (u64 per element)
constexpr size_t OFF_REP   = OFF_H2 + SZ_H2;            // rep accumulator [B][H]
constexpr size_t SZ_REP    = (size_t)B * H;
constexpr size_t WS_FLOATS = OFF_REP + SZ_REP;

// ---------------- prep: transpose + interleave weights, invalidate h tags ----------------
__global__ __launch_bounds__(256) void prep_weights(
    const float* __restrict__ Wf, const float* __restrict__ Wi,
    const float* __restrict__ Wc, const float* __restrict__ Wo,
    const float* __restrict__ bf, const float* __restrict__ bi,
    const float* __restrict__ bc, const float* __restrict__ bo,
    float* __restrict__ ws)
{
    float* WT4 = ws + OFF_WT4;
    float* bI  = ws + OFF_BI;
    int idx = blockIdx.x * 256 + threadIdx.x;            // 65536 threads
    const float* Ws[4] = {Wf, Wi, Wc, Wo};
    #pragma unroll
    for (int j = 0; j < 6; ++j) {
        int item = idx + j * 65536;                      // [0, 393216)
        int k4   = item >> 11;                           // /2048
        int row  = item & 2047;
        int unit = row >> 2, gate = row & 3;
        const float* W = Ws[gate];
        float4 v = *(const float4*)(W + (size_t)unit * K + (size_t)k4 * 4);
        *(float4*)(WT4 + ((size_t)k4 * ROWS + row) * 4) = v;
    }
    if (idx < ROWS) {
        int unit = idx >> 2, gate = idx & 3;
        const float* bs[4] = {bf, bi, bc, bo};
        bI[idx] = bs[gate][unit];
    }
    // zero all tags (tag 0 matches no want >= 2); end-of-dispatch L2 writeback makes
    // these visible to persist's sc-bypass loads (validated R2..R8).
    ((unsigned long long*)(ws + OFF_H2))[idx] = 0ull;    // 2*B*H = 65536 u64 exactly
}

// ---------------- persistent LSTM kernel ----------------
// grid 256 = 32 row-groups x 8 seq-groups; bid = rg*8 + sg; 1 block/CU (deadlock-safe).
// R9: block = 1024 threads = 16 WAVES -> 4 waves/SIMD (R8 proved TLP lever; at
// VGPR<=128 the HW allows 4/SIMD and R8 was grid-limited at 2).
//
// GEMV geometry (keeps R5/R8's validated 384 b128-broadcasts/CU/step, R7 lesson:
// read COUNT is what matters):
//   wave w (0..15) owns k-sixteenth: E k4 = w*4+q (1/lane), H k4 = 64+w*8+q+4jj (2/lane)
//   lane l: q = (l>>3)&3 (4 addr-groups/read = 64B); rows from bits {0,1,2,5}:
//   rl4 = (l&7)|((l>>5)<<3), rows rg*64 + rl4*4 .. +3 (4 rows/lane)
//   -> 12 weight float4/thread, acc[4][8], 384 FMA/thread.
// Partials: DPP row_ror:8 merge (l<->l^8 = q<->q^1, R7-validated primitive) folds
// q-pairs -> 32 slices -> R8's 2-phase write(w<8)+RMW(w>=8) into 16-slice part2
// (32 KB). Reduce: waves 0-7 own seq w (16-slice sum); waves 8-15 SKIP reduce and
// run ahead to next step's prefetch/E-GEMV (slack). All LDS reuse crosses >=1
// barrier: part2 reads (reduce, w<8) end before S1(t+1) (all waves join);
// h_lds(t+1) writes at (d) come after S3(t) > S2(t) > h_lds(t) reads at (f).
//
// REGISTER RULE (R1 failure): weights in ONE wreg[12] float4 array, const indices.
// launch_bounds(1024,4) caps VGPR at 128 (4 waves/SIMD). Spill tripwire: FETCH_SIZE.
//
// Cross-block protocol = tagged scheme (R3..R8): 8-byte (f32 value, u32 tag)
// atomics; producer stores (h, t+2) relaxed agent-scope; consumer staging load IS
// the poll (retry until __all(tags == t+1)). WAR: per-step all-gather bounds skew.
__global__ __launch_bounds__(1024, 4) void lstm_persist(
    float* __restrict__ ws,
    const int* __restrict__ x, const int* __restrict__ mask,
    const float* __restrict__ embed)
{
    __shared__ float emb_lds[2][8][E];                   // 16 KB dbuf (local gather)
    __shared__ float h_lds[8 * H];                       // 16 KB
    __shared__ float part2_lds[8 * 16 * 64];             // 32 KB: [s8][p=0..16][row]

    const int bid = blockIdx.x;
    const int rg  = bid >> 3, sg = bid & 7;
    const int tid = threadIdx.x;
    const int w   = tid >> 6, l = tid & 63;              // w 0..15
    const int q   = (l >> 3) & 3;                        // k sub-slice (4 addr-groups)
    const int rl4 = (l & 7) | ((l >> 5) << 3);           // row-quad 0..15
    const int qhalf = (l >> 4) & 1;                      // q>>1
    const int seq_base = sg * 8;
    const int gate = l & 3, qlane = l >> 2;              // reduce: lane l owns row rg*64+l

    const float4* WT4 = (const float4*)(ws + OFF_WT4);
    const float*  bI  = ws + OFF_BI;
    unsigned long long* h2 = (unsigned long long*)(ws + OFF_H2);
    float* repg = ws + OFF_REP;

    // ---- stationary weights: ONE array, const indices
    // E: wreg[r] = WT4[w*4+q][rowA+r]; H: wreg[4+r*2+jj] = WT4[64+w*8+q+4jj][rowA+r]
    float4 wreg[12];
    {
        const int rowA = rg * 64 + rl4 * 4;
        #pragma unroll
        for (int r = 0; r < 4; ++r)
            wreg[r] = WT4[(size_t)(w * 4 + q) * ROWS + rowA + r];
        #pragma unroll
        for (int jj = 0; jj < 2; ++jj)
            #pragma unroll
            for (int r = 0; r < 4; ++r)
                wreg[4 + r * 2 + jj] = WT4[(size_t)(64 + w * 8 + q + 4 * jj) * ROWS + rowA + r];
    }
    const float breg = bI[rg * 64 + l];                  // bias for the REDUCE row

    // ---- per-owner-lane state (gate==0 lanes): wave w (<8) owns seq (seq_base + w)
    float c0 = 0.f, h0 = 0.f, r0 = 0.f;

    const int sl = tid >> 7, col2 = (tid & 127) * 2;     // emb gather: 1 float2/thread

    // ---- prologue: local emb gather for t=0; h_lds = 0 (no poll at t=0)
    {
        int tok = x[(size_t)(seq_base + sl) * L + 0];
        *(float2*)&emb_lds[0][sl][col2] = *(const float2*)(embed + (size_t)tok * E + col2);
        #pragma unroll
        for (int i = 0; i < 4; ++i) h_lds[tid + i * 1024] = 0.f;
    }
    __syncthreads();

    // ---- main recurrence: 3 barriers per step, zero flags, zero fences
    for (int t = 0; t < L; ++t) {
        const int cur = t & 1, nxt = cur ^ 1;
        const unsigned long long* c2c = h2 + (size_t)cur * B * H + (size_t)seq_base * H;
        unsigned long long*       c2n = h2 + (size_t)nxt * B * H + (size_t)seq_base * H;

        // (a) local emb prefetch for t+1 (plain cached loads, read-only data)
        float2 e0;
        const bool pf = (t + 1) < L;
        if (pf) {
            int tok = x[(size_t)(seq_base + sl) * L + (t + 1)];
            e0 = *(const float2*)(embed + (size_t)tok * E + col2);
        }

        // (b) issue tagged h loads (4 u64/thread); tag check deferred past E-GEMV
        unsigned long long hv[4];
        if (t > 0) {
            #pragma unroll
            for (int i = 0; i < 2; ++i) {
                hv[2 * i]     = __hip_atomic_load(&c2c[i * 2048 + tid * 2],
                                    __ATOMIC_RELAXED, __HIP_MEMORY_SCOPE_AGENT);
                hv[2 * i + 1] = __hip_atomic_load(&c2c[i * 2048 + tid * 2 + 1],
                                    __ATOMIC_RELAXED, __HIP_MEMORY_SCOPE_AGENT);
            }
        }

        // (c) E-GEMV while tagged loads fly: 128 FMAs, 1 b128 read per s8
        float acc[4][8];
        #pragma unroll
        for (int r = 0; r < 4; ++r)
            #pragma unroll
            for (int s8 = 0; s8 < 8; ++s8) acc[r][s8] = 0.f;
        {
            const int off = (w * 4 + q) * 4;
            #pragma unroll
            for (int s8 = 0; s8 < 8; ++s8) {
                float4 c4 = *(const float4*)&emb_lds[cur][s8][off];
                #pragma unroll
                for (int r = 0; r < 4; ++r) {
                    float4 wv = wreg[r];
                    acc[r][s8] = fmaf(wv.x, c4.x, acc[r][s8]);
                    acc[r][s8] = fmaf(wv.y, c4.y, acc[r][s8]);
                    acc[r][s8] = fmaf(wv.z, c4.z, acc[r][s8]);
                    acc[r][s8] = fmaf(wv.w, c4.w, acc[r][s8]);
                }
            }
        }

        // (d) verify tags (retry rare), land h into LDS
        if (t > 0) {
            const unsigned int want = (unsigned int)(t + 1);
            int guard = 0;
            for (;;) {
                bool ok = true;
                #pragma unroll
                for (int i = 0; i < 4; ++i)
                    ok &= ((unsigned int)(hv[i] >> 32) == want);
                if (__all(ok) || ++guard > (1 << 20)) break;
                __builtin_amdgcn_s_sleep(2);
                #pragma unroll
                for (int i = 0; i < 2; ++i) {
                    hv[2 * i]     = __hip_atomic_load(&c2c[i * 2048 + tid * 2],
                                        __ATOMIC_RELAXED, __HIP_MEMORY_SCOPE_AGENT);
                    hv[2 * i + 1] = __hip_atomic_load(&c2c[i * 2048 + tid * 2 + 1],
                                        __ATOMIC_RELAXED, __HIP_MEMORY_SCOPE_AGENT);
                }
            }
            #pragma unroll
            for (int i = 0; i < 2; ++i)
                *(float2*)&h_lds[i * 2048 + tid * 2] = make_float2(
                    __uint_as_float((unsigned int)hv[2 * i]),
                    __uint_as_float((unsigned int)hv[2 * i + 1]));
        }

        // (e) land emb prefetch
        if (pf) *(float2*)&emb_lds[nxt][sl][col2] = e0;
        __syncthreads();                                 // S1: h_lds/emb ready

        // (f) H-GEMV: 256 FMAs, 2 b128 reads per s8
        #pragma unroll
        for (int jj = 0; jj < 2; ++jj) {
            const int off = (w * 8 + q + 4 * jj) * 4;
            #pragma unroll
            for (int s8 = 0; s8 < 8; ++s8) {
                float4 c4 = *(const float4*)&h_lds[s8 * 512 + off];
                #pragma unroll
                for (int r = 0; r < 4; ++r) {
                    float4 wv = wreg[4 + r * 2 + jj];
                    acc[r][s8] = fmaf(wv.x, c4.x, acc[r][s8]);
                    acc[r][s8] = fmaf(wv.y, c4.y, acc[r][s8]);
                    acc[r][s8] = fmaf(wv.z, c4.z, acc[r][s8]);
                    acc[r][s8] = fmaf(wv.w, c4.w, acc[r][s8]);
                }
            }
        }

        // (f1) DPP q-pair merge (lane l <-> l^8 = q <-> q^1, row_ror:8, VALU pipe):
        // both lanes end with the pair sum -> 32 slices -> q&1==0 lanes write.
        #pragma unroll
        for (int r = 0; r < 4; ++r)
            #pragma unroll
            for (int s8 = 0; s8 < 8; ++s8) {
                int a_ = __float_as_int(acc[r][s8]);
                float o = __int_as_float(
                    __builtin_amdgcn_mov_dpp(a_, 0x128, 0xF, 0xF, true)); // row_ror:8
                acc[r][s8] += o;
            }

        // (f2) partials, two-phase into 16 slices (32 KB):
        if (w < 8 && (q & 1) == 0) {                     // phase 1: write slice w*2+qhalf
            const int s = w * 2 + qhalf;
            #pragma unroll
            for (int s8 = 0; s8 < 8; ++s8)
                *(float4*)&part2_lds[(s8 * 16 + s) * 64 + rl4 * 4] =
                    make_float4(acc[0][s8], acc[1][s8], acc[2][s8], acc[3][s8]);
        }
        __syncthreads();                                 // S2
        if (w >= 8 && (q & 1) == 0) {                    // phase 2: RMW slice (w-8)*2+qhalf
            const int s = (w - 8) * 2 + qhalf;
            #pragma unroll
            for (int s8 = 0; s8 < 8; ++s8) {
                float4* p = (float4*)&part2_lds[(s8 * 16 + s) * 64 + rl4 * 4];
                float4 o = *p;
                o.x += acc[0][s8]; o.y += acc[1][s8];
                o.z += acc[2][s8]; o.w += acc[3][s8];
                *p = o;
            }
        }
        __syncthreads();                                 // S3

        // (g) reduce: waves 0-7 own seq w; waves 8-15 skip (run ahead = slack)
        if (w < 8) {
            float a = breg;
            #pragma unroll
            for (int mm = 0; mm < 16; ++mm)
                a += part2_lds[(w * 16 + mm) * 64 + l];
            float act = (gate == 2) ? tanhf(a) : 1.f / (1.f + expf(-a));
            int ab = __float_as_int(act);
            float fg = __int_as_float(__builtin_amdgcn_mov_dpp(ab, 0x00, 0xF, 0xF, true));
            float ig = __int_as_float(__builtin_amdgcn_mov_dpp(ab, 0x55, 0xF, 0xF, true));
            float cg = __int_as_float(__builtin_amdgcn_mov_dpp(ab, 0xAA, 0xF, 0xF, true));
            float og = __int_as_float(__builtin_amdgcn_mov_dpp(ab, 0xFF, 0xF, 0xF, true));
            if (gate == 0) {
                c0 = fg * c0 + ig * cg;                  // c not mask-blended (matches ref)
                float hn = og * tanhf(c0);
                int seq = seq_base + w;
                float mk = (mask[(size_t)seq * L + t] != 0) ? 1.f : 0.f;
                float h = hn * mk + h0 * (1.f - mk);
                h0 = h;
                // single 8B atomic carries value AND readiness -> no release needed
                unsigned long long p64 = (((unsigned long long)(unsigned int)(t + 2)) << 32)
                                       | (unsigned long long)__float_as_uint(h);
                __hip_atomic_store(&c2n[(size_t)w * H + rg * 16 + qlane],
                                   p64, __ATOMIC_RELAXED, __HIP_MEMORY_SCOPE_AGENT);
                r0 += h * mk;
            }
        }
        // NO S4: next iteration's tag check is the only consumer-side gate.
    }

    // ---- epilogue: dump rep registers (unique owner per (seq,unit))
    if (w < 8 && gate == 0)
        repg[(size_t)(seq_base + w) * H + rg * 16 + qlane] = r0;
}

// ---------------- final: rep mean + logits ----------------
__global__ __launch_bounds__(256) void lstm_final(
    const float* __restrict__ ws,
    const int* __restrict__ mask,
    const float* __restrict__ Wfc, const float* __restrict__ bfc,
    float* __restrict__ out)
{
    __shared__ float sred[256];
    __shared__ float srep[H];
    int s = blockIdx.x, tid = threadIdx.x;

    float dsum = 0.f;
    for (int i = tid; i < L; i += 256) dsum += (mask[(size_t)s * L + i] != 0) ? 1.f : 0.f;
    sred[tid] = dsum; __syncthreads();
    for (int off = 128; off > 0; off >>= 1) {
        if (tid < off) sred[tid] += sred[tid + off];
        __syncthreads();
    }
    float denom = fmaxf(sred[0], 1e-9f);
    __syncthreads();

    const float* repa = ws + OFF_REP + (size_t)s * H;
    for (int i = tid; i < H; i += 256) {
        float r = repa[i] / denom;
        srep[i] = r;
        out[128 + (size_t)s * H + i] = r;
    }
    __syncthreads();

    for (int c = 0; c < 2; ++c) {
        float d = 0.f;
        for (int i = tid; i < H; i += 256) d += srep[i] * Wfc[(size_t)c * H + i];
        sred[tid] = d; __syncthreads();
        for (int off = 128; off > 0; off >>= 1) {
            if (tid < off) sred[tid] += sred[tid + off];
            __syncthreads();
        }
        if (tid == 0) out[(size_t)s * 2 + c] = sred[0] + bfc[c];
        __syncthreads();
    }
}

// ---------------- host ----------------
extern "C" void kernel_launch(void* const* d_in, const int* in_sizes, int n_in,
                              void* d_out, int out_size, void* d_ws, size_t ws_size,
                              hipStream_t stream)
{
    const int*   x     = (const int*)d_in[0];
    const int*   mask  = (const int*)d_in[1];
    const float* embed = (const float*)d_in[2];
    const float* Wf = (const float*)d_in[3];  const float* bf = (const float*)d_in[4];
    const float* Wi = (const float*)d_in[5];  const float* bi = (const float*)d_in[6];
    const float* Wc = (const float*)d_in[7];  const float* bc = (const float*)d_in[8];
    const float* Wo = (const float*)d_in[9];  const float* bo = (const float*)d_in[10];
    const float* Wfc = (const float*)d_in[11]; const float* bfc = (const float*)d_in[12];
    float* out = (float*)d_out;
    float* ws  = (float*)d_ws;

    if (ws_size < WS_FLOATS * sizeof(float)) {
        return; // leave output poisoned so the failure mode is unambiguous
    }

    prep_weights<<<256, 256, 0, stream>>>(Wf, Wi, Wc, Wo, bf, bi, bc, bo, ws);
    lstm_persist<<<256, 1024, 0, stream>>>(ws, x, mask, embed);
    lstm_final<<<64, 256, 0, stream>>>(ws, mask, Wfc, bfc, out);
}